// Round 6
// baseline (269.509 us; speedup 1.0000x reference)
//
#include <hip/hip_runtime.h>
#include <hip/hip_cooperative_groups.h>
#include <math.h>

namespace cg = cooperative_groups;

typedef unsigned int u32;
typedef unsigned short ushort_t;
typedef __attribute__((ext_vector_type(8))) short short8;
typedef __attribute__((ext_vector_type(4))) float f32x4;
typedef __attribute__((ext_vector_type(16))) float f32x16;

#define B_G 16
#define S_MAX 512
#define NH 8
#define DH 32
#define HD 256
#define FFD 1024
#define ADJW 16            // u32 words per adjacency row (512 bits)

__device__ __forceinline__ ushort_t f2bf(float f) {
  u32 u = __float_as_uint(f);
  u += 0x7fffu + ((u >> 16) & 1u);
  return (ushort_t)(u >> 16);
}

__device__ __forceinline__ void gll16(const void* g, void* l) {
  __builtin_amdgcn_global_load_lds(
      (const __attribute__((address_space(1))) unsigned int*)g,
      (__attribute__((address_space(3))) unsigned int*)l, 16, 0, 0);
}

__device__ __forceinline__ int bsearch_g(const int* __restrict__ batch, int Nn, int g) {
  int lo = 0, hi = Nn;
  while (lo < hi) { int mid = (lo + hi) >> 1; if (batch[mid] < g) lo = mid + 1; else hi = mid; }
  return lo;
}

// ---- 128x128 GEMM tile engine, 8 waves (2M x 4N, wave=64x32), BK=64, bf16 out ----
template<bool RELU>
__device__ __forceinline__ void gemm128(const ushort_t* __restrict__ A,
    const ushort_t* __restrict__ W, const float* __restrict__ bias,
    ushort_t* __restrict__ outB, int arow0, int bcol0, int Kdim, int Ncols,
    char* smem, int tid) {
  ushort_t* As = (ushort_t*)smem;               // 16KB
  ushort_t* Bs = (ushort_t*)(smem + 16384);     // 16KB
  int wid = tid >> 6, lane = tid & 63;
  int wm = wid >> 2, wn = wid & 3;

  const ushort_t* gA[2]; const ushort_t* gB[2];
  ushort_t *lA[2], *lB[2];
  #pragma unroll
  for (int i = 0; i < 2; i++) {
    int s = i * 512 + tid;
    int r = s >> 3, ck = (s & 7) ^ (r & 7);
    gA[i] = A + (size_t)(arow0 + r) * Kdim + ck * 8;
    gB[i] = W + (size_t)(bcol0 + r) * Kdim + ck * 8;
    lA[i] = As + (i * 512 + wid * 64) * 8;
    lB[i] = Bs + (i * 512 + wid * 64) * 8;
  }

  f32x4 acc[4][2];
  #pragma unroll
  for (int i = 0; i < 4; i++)
    #pragma unroll
    for (int j = 0; j < 2; j++) { f32x4 z = {0.f,0.f,0.f,0.f}; acc[i][j] = z; }

  for (int k0 = 0; k0 < Kdim; k0 += 64) {
    __syncthreads();
    #pragma unroll
    for (int i = 0; i < 2; i++) { gll16(gA[i] + k0, lA[i]); gll16(gB[i] + k0, lB[i]); }
    asm volatile("s_waitcnt vmcnt(0)" ::: "memory");
    __syncthreads();
    #pragma unroll
    for (int ks = 0; ks < 2; ks++) {
      short8 af[4], bfv[2];
      #pragma unroll
      for (int i = 0; i < 4; i++) {
        int row = wm * 64 + i * 16 + (lane & 15);
        int ck = (ks * 4 + (lane >> 4)) ^ (row & 7);
        af[i] = *(const short8*)&As[row * 64 + ck * 8];
      }
      #pragma unroll
      for (int j = 0; j < 2; j++) {
        int row = wn * 32 + j * 16 + (lane & 15);
        int ck = (ks * 4 + (lane >> 4)) ^ (row & 7);
        bfv[j] = *(const short8*)&Bs[row * 64 + ck * 8];
      }
      #pragma unroll
      for (int i = 0; i < 4; i++)
        #pragma unroll
        for (int j = 0; j < 2; j++)
          acc[i][j] = __builtin_amdgcn_mfma_f32_16x16x32_bf16(af[i], bfv[j], acc[i][j], 0, 0, 0);
    }
  }

  float bj[2];
  int colb[2];
  #pragma unroll
  for (int j = 0; j < 2; j++) {
    colb[j] = bcol0 + wn * 32 + j * 16 + (lane & 15);
    bj[j] = bias[colb[j]];
  }
  #pragma unroll
  for (int i = 0; i < 4; i++) {
    #pragma unroll
    for (int r = 0; r < 4; r++) {
      int row = arow0 + wm * 64 + i * 16 + (lane >> 4) * 4 + r;
      #pragma unroll
      for (int j = 0; j < 2; j++) {
        float v = acc[i][j][r] + bj[j];
        if (RELU) v = fmaxf(v, 0.f);
        outB[(size_t)row * Ncols + colb[j]] = f2bf(v);
      }
    }
  }
}

// ---- 32x256 GEMM + residual + LayerNorm engine, 8 waves (wave=32x32), BK=64 ----
template<bool OUTBF>
__device__ __forceinline__ void gemm_ln32(const ushort_t* __restrict__ A,
    const ushort_t* __restrict__ W, const float* __restrict__ bias,
    const float* __restrict__ R, const float* __restrict__ gamma,
    const float* __restrict__ beta, float* __restrict__ outF,
    ushort_t* __restrict__ outBf, int row0, int Kdim, char* smem, int tid) {
  ushort_t* As = (ushort_t*)smem;                 // 4KB  (32x64)
  ushort_t* Bs = (ushort_t*)(smem + 4096);        // 32KB (256x64)
  float* red_s = (float*)(smem + 4096 + 32768);   // [32][8]
  float* red_q = red_s + 256;                     // [32][8]
  int wid = tid >> 6, lane = tid & 63;
  int wn = wid;

  const ushort_t* gA = nullptr; ushort_t* lA = nullptr;
  if (tid < 256) {
    int s = tid, r = s >> 3, ck = (s & 7) ^ (r & 7);
    gA = A + (size_t)(row0 + r) * Kdim + ck * 8;
    lA = As + (wid * 64) * 8;
  }
  const ushort_t* gB[4]; ushort_t* lB[4];
  #pragma unroll
  for (int i = 0; i < 4; i++) {
    int s = i * 512 + tid;
    int r = s >> 3, ck = (s & 7) ^ (r & 7);
    gB[i] = W + (size_t)r * Kdim + ck * 8;
    lB[i] = Bs + (i * 512 + wid * 64) * 8;
  }

  f32x4 acc[2][2];
  #pragma unroll
  for (int i = 0; i < 2; i++)
    #pragma unroll
    for (int j = 0; j < 2; j++) { f32x4 z = {0.f,0.f,0.f,0.f}; acc[i][j] = z; }

  for (int k0 = 0; k0 < Kdim; k0 += 64) {
    __syncthreads();
    if (tid < 256) gll16(gA + k0, lA);
    #pragma unroll
    for (int i = 0; i < 4; i++) gll16(gB[i] + k0, lB[i]);
    asm volatile("s_waitcnt vmcnt(0)" ::: "memory");
    __syncthreads();
    #pragma unroll
    for (int ks = 0; ks < 2; ks++) {
      short8 af[2], bfv[2];
      #pragma unroll
      for (int i = 0; i < 2; i++) {
        int row = i * 16 + (lane & 15);
        int ck = (ks * 4 + (lane >> 4)) ^ (row & 7);
        af[i] = *(const short8*)&As[row * 64 + ck * 8];
      }
      #pragma unroll
      for (int j = 0; j < 2; j++) {
        int row = wn * 32 + j * 16 + (lane & 15);
        int ck = (ks * 4 + (lane >> 4)) ^ (row & 7);
        bfv[j] = *(const short8*)&Bs[row * 64 + ck * 8];
      }
      #pragma unroll
      for (int i = 0; i < 2; i++)
        #pragma unroll
        for (int j = 0; j < 2; j++)
          acc[i][j] = __builtin_amdgcn_mfma_f32_16x16x32_bf16(af[i], bfv[j], acc[i][j], 0, 0, 0);
    }
  }

  int col[2]; float bc[2], gm[2], bt[2];
  #pragma unroll
  for (int j = 0; j < 2; j++) {
    col[j] = wn * 32 + j * 16 + (lane & 15);
    bc[j] = bias[col[j]]; gm[j] = gamma[col[j]]; bt[j] = beta[col[j]];
  }
  // add bias + residual; per-row partial sums over this wave's 32 cols
  #pragma unroll
  for (int i = 0; i < 2; i++) {
    #pragma unroll
    for (int r = 0; r < 4; r++) {
      int row_l = i * 16 + (lane >> 4) * 4 + r;
      const float* Rrow = R + (size_t)(row0 + row_l) * HD;
      float s = 0.f, q = 0.f;
      #pragma unroll
      for (int j = 0; j < 2; j++) {
        float v = acc[i][j][r] + bc[j] + Rrow[col[j]];
        acc[i][j][r] = v;
        s += v; q += v * v;
      }
      #pragma unroll
      for (int o = 1; o < 16; o <<= 1) { s += __shfl_xor(s, o, 64); q += __shfl_xor(q, o, 64); }
      if ((lane & 15) == 0) { red_s[row_l * 8 + wn] = s; red_q[row_l * 8 + wn] = q; }
    }
  }
  __syncthreads();
  #pragma unroll
  for (int i = 0; i < 2; i++) {
    #pragma unroll
    for (int r = 0; r < 4; r++) {
      int row_l = i * 16 + (lane >> 4) * 4 + r;
      float ssum = 0.f, qsum = 0.f;
      #pragma unroll
      for (int w2 = 0; w2 < 8; w2++) { ssum += red_s[row_l * 8 + w2]; qsum += red_q[row_l * 8 + w2]; }
      float mu = ssum * (1.f / HD);
      float var = qsum * (1.f / HD) - mu * mu;
      float inv = rsqrtf(var + 1e-5f);
      size_t rb = (size_t)(row0 + row_l) * HD;
      #pragma unroll
      for (int j = 0; j < 2; j++) {
        float v = (acc[i][j][r] - mu) * inv * gm[j] + bt[j];
        outF[rb + col[j]] = v;
        if (OUTBF) outBf[rb + col[j]] = f2bf(v);
      }
    }
  }
  __syncthreads();   // red/Bs reused by caller's next phase
}

// ================= fused whole-layer cooperative kernel =================
__global__ __launch_bounds__(512, 2) void k_fused(
    const float* __restrict__ h,
    const float* __restrict__ Wq, const float* __restrict__ bq,
    const float* __restrict__ Wk, const float* __restrict__ bk,
    const float* __restrict__ Wo, const float* __restrict__ bo,
    const float* __restrict__ W1, const float* __restrict__ b1,
    const float* __restrict__ W2, const float* __restrict__ b2,
    const float* __restrict__ g1, const float* __restrict__ be1,
    const float* __restrict__ g2, const float* __restrict__ be2,
    const int* __restrict__ batch, const int* __restrict__ ei,
    int Nn, int E,
    ushort_t* __restrict__ xb, ushort_t* __restrict__ qkb,
    float* __restrict__ h1, ushort_t* __restrict__ h1b, ushort_t* __restrict__ ff1b,
    ushort_t* __restrict__ Wqkb, ushort_t* __restrict__ Wob,
    ushort_t* __restrict__ W1b, ushort_t* __restrict__ W2b,
    float* __restrict__ bqk, u32* __restrict__ adj, int* __restrict__ offs,
    float* __restrict__ outF) {
  cg::grid_group grid = cg::this_grid();
  __shared__ __align__(16) char smem[81920];
  int blk = blockIdx.x, tid = threadIdx.x;

  // ---------- P1: adj zero | offsets | bias concat | weight cvt | dense scatter ----------
  adj[blk * 512 + tid] = 0u;                       // 256*512 = 128K words = 512KB
  if (blk == 0 && tid <= B_G)
    offs[tid] = (tid == B_G) ? Nn : bsearch_g(batch, Nn, tid);
  if (blk == 1)
    bqk[tid] = (tid < HD) ? bq[tid] : bk[tid - HD];
  {
    int u = blk * 512 + tid;                       // 90112 units of 8 floats
    if (u < 90112) {
      const float* src; ushort_t* dst; int off;
      if (u < 8192)       { src = Wq; dst = Wqkb;         off = u; }
      else if (u < 16384) { src = Wk; dst = Wqkb + 65536; off = u - 8192; }
      else if (u < 24576) { src = Wo; dst = Wob;          off = u - 16384; }
      else if (u < 57344) { src = W1; dst = W1b;          off = u - 24576; }
      else                { src = W2; dst = W2b;          off = u - 57344; }
      size_t i = (size_t)off * 8;
      float4 v0 = *(const float4*)&src[i];
      float4 v1 = *(const float4*)&src[i + 4];
      uint4 pk;
      pk.x = (u32)f2bf(v0.x) | ((u32)f2bf(v0.y) << 16);
      pk.y = (u32)f2bf(v0.z) | ((u32)f2bf(v0.w) << 16);
      pk.z = (u32)f2bf(v1.x) | ((u32)f2bf(v1.y) << 16);
      pk.w = (u32)f2bf(v1.z) | ((u32)f2bf(v1.w) << 16);
      *(uint4*)&dst[i] = pk;
    }
  }
  #pragma unroll
  for (int it = 0; it < 4; it++) {                 // dense scatter, inline bsearch
    int T = it * 131072 + blk * 512 + tid;
    int row = T >> 6, c = T & 63;
    int b = row >> 9, pos = row & 511;
    int lo = bsearch_g(batch, Nn, b);
    int hi2 = bsearch_g(batch, Nn, b + 1);
    uint2 pk = {0u, 0u};
    if (pos < hi2 - lo) {
      float4 v = ((const float4*)(h + (size_t)(lo + pos) * HD))[c];
      pk.x = (u32)f2bf(v.x) | ((u32)f2bf(v.y) << 16);
      pk.y = (u32)f2bf(v.z) | ((u32)f2bf(v.w) << 16);
    }
    *(uint2*)(xb + (size_t)row * HD + c * 4) = pk;
  }
  grid.sync();

  // ---------- P2: edge atomicOr + QK GEMM ----------
  {
    int e = blk * 400 + tid;
    if (tid < 400 && e < E) {
      int s = ei[e], d = ei[E + e];
      int b = batch[s];
      int o = offs[b];
      atomicOr(&adj[(b * S_MAX + (s - o)) * ADJW + ((d - o) >> 5)], 1u << ((d - o) & 31));
    }
    int bm = blk & 63, bn = blk >> 6;
    gemm128<false>(xb, Wqkb, bqk, qkb, bm * 128, bn * 128, HD, 512, smem, tid);
  }
  grid.sync();

  // ---------- P3: fused masked attention (unit = b|h|half, 8 waves x 32 q-rows) ----------
  {
    int b = blk >> 4, hh = (blk >> 1) & 7, half = blk & 1;
    int nstart = offs[b], len = offs[b + 1] - nstart;
    ushort_t* K_lds = (ushort_t*)smem;             // 32KB [4][512][8]
    ushort_t* Kt_lds = (ushort_t*)(smem + 32768);  // 32KB [64][32][8]
    ushort_t* P_lds = (ushort_t*)(smem + 65536);   // 16KB [8][4][32][8]

    const ushort_t* kg = qkb + (size_t)(b * S_MAX) * 512 + 256 + hh * 32;
    {
      int t = tid;
      const uint4* src = (const uint4*)(kg + (size_t)t * 512);
      uint4 v0 = src[0], v1 = src[1], v2 = src[2], v3 = src[3];
      *(uint4*)&K_lds[0 * 4096 + t * 8] = v0;
      *(uint4*)&K_lds[1 * 4096 + t * 8] = v1;
      *(uint4*)&K_lds[2 * 4096 + t * 8] = v2;
      *(uint4*)&K_lds[3 * 4096 + t * 8] = v3;
    }
    __syncthreads();
    {
      int d = tid & 31, tg = tid >> 5;
      int cc = d >> 3, e2 = d & 7;
      #pragma unroll
      for (int i = 0; i < 4; i++) {
        int t0 = tg * 32 + i * 8;
        u32 w0 = (u32)K_lds[cc * 4096 + (t0 + 0) * 8 + e2] | ((u32)K_lds[cc * 4096 + (t0 + 1) * 8 + e2] << 16);
        u32 w1 = (u32)K_lds[cc * 4096 + (t0 + 2) * 8 + e2] | ((u32)K_lds[cc * 4096 + (t0 + 3) * 8 + e2] << 16);
        u32 w2 = (u32)K_lds[cc * 4096 + (t0 + 4) * 8 + e2] | ((u32)K_lds[cc * 4096 + (t0 + 5) * 8 + e2] << 16);
        u32 w3 = (u32)K_lds[cc * 4096 + (t0 + 6) * 8 + e2] | ((u32)K_lds[cc * 4096 + (t0 + 7) * 8 + e2] << 16);
        uint4 pk = {w0, w1, w2, w3};
        *(uint4*)&Kt_lds[(t0 >> 3) * 256 + d * 8] = pk;
      }
    }
    __syncthreads();

    int w = tid >> 6, lane = tid & 63;
    int q0w = half * 256 + w * 32;
    if (q0w < len) {                               // skip, not return (grid.sync below)
      int lq = lane & 31, hf = lane >> 5;
      int q_abs = q0w + lq;
      const float SCALE = 0.17677669529663687f;

      size_t qrow = (size_t)(b * S_MAX + q_abs) * 512 + hh * 32;
      short8 qf0 = *(const short8*)(qkb + qrow + hf * 8);
      short8 qf1 = *(const short8*)(qkb + qrow + 16 + hf * 8);

      const uint4* ap = (const uint4*)(adj + (size_t)(b * S_MAX + q_abs) * ADJW);
      uint4 a0 = ap[0], a1 = ap[1], a2 = ap[2], a3 = ap[3];
      u32 aw[16] = {a0.x, a0.y, a0.z, a0.w, a1.x, a1.y, a1.z, a1.w,
                    a2.x, a2.y, a2.z, a2.w, a3.x, a3.y, a3.z, a3.w};

      f32x16 oacc = {0.f,0.f,0.f,0.f,0.f,0.f,0.f,0.f,0.f,0.f,0.f,0.f,0.f,0.f,0.f,0.f};
      float lsum = 0.f;

      #pragma unroll
      for (int tt = 0; tt < 16; tt++) {
        int t0 = tt * 32;
        short8 ka0 = *(const short8*)&K_lds[hf * 4096 + (t0 + lq) * 8];
        short8 ka1 = *(const short8*)&K_lds[(2 + hf) * 4096 + (t0 + lq) * 8];
        f32x16 sc = {0.f,0.f,0.f,0.f,0.f,0.f,0.f,0.f,0.f,0.f,0.f,0.f,0.f,0.f,0.f,0.f};
        sc = __builtin_amdgcn_mfma_f32_32x32x16_bf16(ka0, qf0, sc, 0, 0, 0);
        sc = __builtin_amdgcn_mfma_f32_32x32x16_bf16(ka1, qf1, sc, 0, 0, 0);
        u32 word = aw[tt];
        float p[16];
        #pragma unroll
        for (int r = 0; r < 16; r++) {
          int tb = (r & 3) + 8 * (r >> 2) + 4 * hf;
          float pe = __expf(sc[r] * SCALE);
          p[r] = ((word >> tb) & 1u) ? 0.f : pe;
          lsum += p[r];
        }
        #pragma unroll
        for (int g = 0; g < 4; g++) {
          u32 lo = (u32)f2bf(p[4 * g]) | ((u32)f2bf(p[4 * g + 1]) << 16);
          u32 hi = (u32)f2bf(p[4 * g + 2]) | ((u32)f2bf(p[4 * g + 3]) << 16);
          uint2 pk = {lo, hi};
          *(uint2*)&P_lds[w * 1024 + g * 256 + lq * 8 + hf * 4] = pk;
        }
        short8 va0 = *(const short8*)&Kt_lds[(t0 / 8 + hf) * 256 + lq * 8];
        short8 va1 = *(const short8*)&Kt_lds[(t0 / 8 + 2 + hf) * 256 + lq * 8];
        short8 pb0 = *(const short8*)&P_lds[w * 1024 + hf * 256 + lq * 8];
        short8 pb1 = *(const short8*)&P_lds[w * 1024 + (2 + hf) * 256 + lq * 8];
        oacc = __builtin_amdgcn_mfma_f32_32x32x16_bf16(va0, pb0, oacc, 0, 0, 0);
        oacc = __builtin_amdgcn_mfma_f32_32x32x16_bf16(va1, pb1, oacc, 0, 0, 0);
      }

      float ltot = lsum + __shfl_xor(lsum, 32, 64);
      float inv = 1.f / ltot;
      if (q_abs < len) {
        int node = nstart + q_abs;
        ushort_t* op = xb + (size_t)node * HD + hh * DH;   // attO aliases xb
        #pragma unroll
        for (int g = 0; g < 4; g++) {
          float v0 = oacc[4 * g] * inv, v1 = oacc[4 * g + 1] * inv;
          float v2 = oacc[4 * g + 2] * inv, v3 = oacc[4 * g + 3] * inv;
          u32 lo = (u32)f2bf(v0) | ((u32)f2bf(v1) << 16);
          u32 hi = (u32)f2bf(v2) | ((u32)f2bf(v3) << 16);
          uint2 pk = {lo, hi};
          *(uint2*)(op + g * 8 + hf * 4) = pk;
        }
      }
    }
  }
  grid.sync();

  // ---------- P4: out-proj + residual(h) + LN1 ----------
  if (blk < 200)
    gemm_ln32<true>(xb, Wob, bo, h, g1, be1, h1, h1b, blk * 32, HD, smem, tid);
  grid.sync();

  // ---------- P5: FFN up + relu (400 tiles, grid-stride) ----------
  for (int t = blk; t < 400; t += 256) {
    int tm = t % 50, tn = t / 50;
    gemm128<true>(h1b, W1b, b1, ff1b, tm * 128, tn * 128, HD, FFD, smem, tid);
  }
  grid.sync();

  // ---------- P6: FFN down + residual(h1) + LN2 -> out ----------
  if (blk < 200)
    gemm_ln32<false>(ff1b, W2b, b2, h1, g2, be2, outF, nullptr, blk * 32, FFD, smem, tid);
}

extern "C" void kernel_launch(void* const* d_in, const int* in_sizes, int n_in,
                              void* d_out, int out_size, void* d_ws, size_t ws_size,
                              hipStream_t stream) {
  const float* h   = (const float*)d_in[0];
  const float* Wq  = (const float*)d_in[1];
  const float* bq  = (const float*)d_in[2];
  const float* Wk  = (const float*)d_in[3];
  const float* bk  = (const float*)d_in[4];
  // d_in[5], d_in[6] (Wv, bv) unused: reference V uses the K projection
  const float* Wo  = (const float*)d_in[7];
  const float* bo  = (const float*)d_in[8];
  const float* W1  = (const float*)d_in[9];
  const float* b1  = (const float*)d_in[10];
  const float* W2  = (const float*)d_in[11];
  const float* b2  = (const float*)d_in[12];
  const float* g1  = (const float*)d_in[13];
  const float* be1 = (const float*)d_in[14];
  const float* g2  = (const float*)d_in[15];
  const float* be2 = (const float*)d_in[16];
  const int* batch = (const int*)d_in[17];
  const int* ei    = (const int*)d_in[18];
  int N = in_sizes[0] / HD;       // 6400
  int E = in_sizes[18] / 2;       // 102400

  // workspace layout (~38 MB)
  char* ws = (char*)d_ws;
  ushort_t* xb    = (ushort_t*)(ws);                        // 4MB [8192,256] bf16 (later attO)
  ushort_t* qkb   = (ushort_t*)(ws + ((size_t)4 << 20));    // 8MB [8192,512] bf16
  float*    h1    = (float*)(ws + ((size_t)12 << 20));      // 6.4MB fp32
  ushort_t* h1b   = (ushort_t*)(ws + ((size_t)19 << 20));   // 3.2MB
  ushort_t* ff1b  = (ushort_t*)(ws + ((size_t)23 << 20));   // 12.8MB
  char* wbase = ws + ((size_t)36 << 20);
  ushort_t* Wqkb = (ushort_t*)(wbase);                      // 256KB [512,256]
  ushort_t* Wob  = (ushort_t*)(wbase + (256 << 10));        // 128KB
  ushort_t* W1b  = (ushort_t*)(wbase + (384 << 10));        // 512KB [1024,256]
  ushort_t* W2b  = (ushort_t*)(wbase + (896 << 10));        // 512KB [256,1024]
  float*    bqk  = (float*)(wbase + (1408 << 10));          // 2KB  [512]
  u32*      adj  = (u32*)(wbase + (1536 << 10));            // 512KB
  int*      offs = (int*)(ws + ((size_t)38 << 20));         // 128B
  float*    outF = (float*)d_out;

  void* kargs[] = {
    (void*)&h, (void*)&Wq, (void*)&bq, (void*)&Wk, (void*)&bk,
    (void*)&Wo, (void*)&bo, (void*)&W1, (void*)&b1,
    (void*)&W2, (void*)&b2, (void*)&g1, (void*)&be1,
    (void*)&g2, (void*)&be2, (void*)&batch, (void*)&ei,
    (void*)&N, (void*)&E,
    (void*)&xb, (void*)&qkb, (void*)&h1, (void*)&h1b, (void*)&ff1b,
    (void*)&Wqkb, (void*)&Wob, (void*)&W1b, (void*)&W2b,
    (void*)&bqk, (void*)&adj, (void*)&offs, (void*)&outF
  };
  hipLaunchCooperativeKernel((void*)k_fused, dim3(256), dim3(512), kargs, 0, stream);
}

// Round 7
// 90.647 us; speedup vs baseline: 2.9732x; 2.9732x over previous
//
#include <hip/hip_runtime.h>
#include <math.h>

typedef unsigned int u32;
typedef unsigned short ushort_t;
typedef __attribute__((ext_vector_type(8))) short short8;
typedef __attribute__((ext_vector_type(4))) float f32x4;
typedef __attribute__((ext_vector_type(16))) float f32x16;

#define B_G 16
#define S_MAX 512
#define NH 8
#define DH 32
#define HD 256
#define FFD 1024
#define ADJW 16            // u32 words per adjacency row (512 bits)

__device__ __forceinline__ ushort_t f2bf(float f) {
  u32 u = __float_as_uint(f);
  u += 0x7fffu + ((u >> 16) & 1u);
  return (ushort_t)(u >> 16);
}

__device__ __forceinline__ void gll16(const void* g, void* l) {
  __builtin_amdgcn_global_load_lds(
      (const __attribute__((address_space(1))) unsigned int*)g,
      (__attribute__((address_space(3))) unsigned int*)l, 16, 0, 0);
}

// ---------- prep: zero adj (512KB) + offsets + bias concat ----------
__global__ __launch_bounds__(256) void k_prep(u32* __restrict__ adj,
    const int* __restrict__ batch, int N, int* __restrict__ offs,
    const float* __restrict__ bq, const float* __restrict__ bk,
    float* __restrict__ bqk) {
  int tid = threadIdx.x, blk = blockIdx.x;
  uint4 z = {0u, 0u, 0u, 0u};
  ((uint4*)adj)[blk * 256 + tid] = z;
  if (blk == 0) {
    bqk[tid] = bq[tid];
    bqk[HD + tid] = bk[tid];
    if (tid <= B_G) {
      if (tid == B_G) { offs[B_G] = N; }
      else {
        int lo = 0, hi = N;
        while (lo < hi) { int mid = (lo + hi) >> 1; if (batch[mid] < tid) lo = mid + 1; else hi = mid; }
        offs[tid] = lo;
      }
    }
  }
}

// ---------- mega prep: dense-scatter+zero | adjacency | weight cvt ----------
__global__ __launch_bounds__(256) void k_mega(
    const float* __restrict__ h, const int* __restrict__ offs, ushort_t* __restrict__ xb,
    const int* __restrict__ ei, int E, const int* __restrict__ batch, u32* __restrict__ adj,
    const float* __restrict__ wa, const float* __restrict__ wb, const float* __restrict__ wc,
    const float* __restrict__ wd, const float* __restrict__ we,
    ushort_t* __restrict__ oa, ushort_t* __restrict__ ob, ushort_t* __restrict__ oc,
    ushort_t* __restrict__ od, ushort_t* __restrict__ oe) {
  int blk = blockIdx.x, tid = threadIdx.x;
  if (blk < 2048) {
    int row = blk * 4 + (tid >> 6);
    int c = tid & 63;
    int b = row >> 9, pos = row & 511;
    int len = offs[b + 1] - offs[b];
    uint2 pk = {0u, 0u};
    if (pos < len) {
      int node = offs[b] + pos;
      float4 v = ((const float4*)(h + (size_t)node * HD))[c];
      pk.x = (u32)f2bf(v.x) | ((u32)f2bf(v.y) << 16);
      pk.y = (u32)f2bf(v.z) | ((u32)f2bf(v.w) << 16);
    }
    *(uint2*)(xb + (size_t)row * HD + c * 4) = pk;
  } else if (blk < 2448) {
    int e = (blk - 2048) * 256 + tid;
    if (e >= E) return;
    int s = ei[e], d = ei[E + e];
    int b = batch[s];
    int o = offs[b];
    atomicOr(&adj[(b * S_MAX + (s - o)) * ADJW + ((d - o) >> 5)], 1u << ((d - o) & 31));
  } else {
    int bb = blk - 2448;
    const float* src; ushort_t* dst; int off;
    if (bb < 32)       { src = wa; dst = oa; off = bb; }
    else if (bb < 64)  { src = wb; dst = ob; off = bb - 32; }
    else if (bb < 96)  { src = wc; dst = oc; off = bb - 64; }
    else if (bb < 224) { src = wd; dst = od; off = bb - 96; }
    else               { src = we; dst = oe; off = bb - 224; }
    size_t i = (size_t)off * 2048 + tid * 8;
    float4 v0 = *(const float4*)&src[i];
    float4 v1 = *(const float4*)&src[i + 4];
    uint4 pk;
    pk.x = (u32)f2bf(v0.x) | ((u32)f2bf(v0.y) << 16);
    pk.y = (u32)f2bf(v0.z) | ((u32)f2bf(v0.w) << 16);
    pk.z = (u32)f2bf(v1.x) | ((u32)f2bf(v1.y) << 16);
    pk.w = (u32)f2bf(v1.z) | ((u32)f2bf(v1.w) << 16);
    *(uint4*)&dst[i] = pk;
  }
}

// ---------- MFMA bf16 GEMM, 128x128 tile, BK=64, 512 thr (8 waves 2x4) ----------
// 2-phase pipeline: issue next K-tile DMA before computing current; raw s_barrier
// + single vmcnt(0) per step (avoids __syncthreads' implicit full drain).
template<bool RELU, bool OUTBF>
__global__ __launch_bounds__(512) void k_mgemm(const ushort_t* __restrict__ A,
    const ushort_t* __restrict__ W, const float* __restrict__ bias,
    void* __restrict__ Cout, int Ncols, int Kdim) {
  __shared__ __align__(16) ushort_t As[2][128 * 64];   // 32KB
  __shared__ __align__(16) ushort_t Bs[2][128 * 64];   // 32KB
  int tid = threadIdx.x;
  int wid = tid >> 6, lane = tid & 63;
  int wm = wid >> 2, wn = wid & 3;
  int arow0 = blockIdx.x * 128, bcol0 = blockIdx.y * 128;

  const ushort_t* gA[2]; const ushort_t* gB[2];
  int dofs[2];
  #pragma unroll
  for (int i = 0; i < 2; i++) {
    int s = i * 512 + tid;
    int r = s >> 3, ck = (s & 7) ^ (r & 7);
    gA[i] = A + (size_t)(arow0 + r) * Kdim + ck * 8;
    gB[i] = W + (size_t)(bcol0 + r) * Kdim + ck * 8;
    dofs[i] = (i * 512 + wid * 64) * 8;
  }

  f32x4 acc[4][2];
  #pragma unroll
  for (int i = 0; i < 4; i++)
    #pragma unroll
    for (int j = 0; j < 2; j++) { f32x4 z = {0.f,0.f,0.f,0.f}; acc[i][j] = z; }

  // prologue: stage K-step 0 into buf 0
  #pragma unroll
  for (int i = 0; i < 2; i++) { gll16(gA[i], &As[0][dofs[i]]); gll16(gB[i], &Bs[0][dofs[i]]); }
  asm volatile("s_waitcnt vmcnt(0)" ::: "memory");
  __builtin_amdgcn_s_barrier();

  int nsteps = Kdim >> 6;
  int cur = 0;
  for (int ks = 0; ks < nsteps; ks++) {
    if (ks + 1 < nsteps) {
      int k0n = (ks + 1) << 6;
      #pragma unroll
      for (int i = 0; i < 2; i++) {
        gll16(gA[i] + k0n, &As[cur ^ 1][dofs[i]]);
        gll16(gB[i] + k0n, &Bs[cur ^ 1][dofs[i]]);
      }
    }
    #pragma unroll
    for (int kk = 0; kk < 2; kk++) {
      short8 af[4], bfv[2];
      #pragma unroll
      for (int i = 0; i < 4; i++) {
        int row = wm * 64 + i * 16 + (lane & 15);
        int ck = (kk * 4 + (lane >> 4)) ^ (row & 7);
        af[i] = *(const short8*)&As[cur][row * 64 + ck * 8];
      }
      #pragma unroll
      for (int j = 0; j < 2; j++) {
        int row = wn * 32 + j * 16 + (lane & 15);
        int ck = (kk * 4 + (lane >> 4)) ^ (row & 7);
        bfv[j] = *(const short8*)&Bs[cur][row * 64 + ck * 8];
      }
      #pragma unroll
      for (int i = 0; i < 4; i++)
        #pragma unroll
        for (int j = 0; j < 2; j++)
          acc[i][j] = __builtin_amdgcn_mfma_f32_16x16x32_bf16(af[i], bfv[j], acc[i][j], 0, 0, 0);
    }
    asm volatile("s_waitcnt vmcnt(0)" ::: "memory");
    __builtin_amdgcn_s_barrier();
    cur ^= 1;
  }

  float bj[2]; int colb[2];
  #pragma unroll
  for (int j = 0; j < 2; j++) {
    colb[j] = bcol0 + wn * 32 + j * 16 + (lane & 15);
    bj[j] = bias[colb[j]];
  }
  #pragma unroll
  for (int i = 0; i < 4; i++) {
    #pragma unroll
    for (int r = 0; r < 4; r++) {
      int row = arow0 + wm * 64 + i * 16 + (lane >> 4) * 4 + r;
      #pragma unroll
      for (int j = 0; j < 2; j++) {
        float v = acc[i][j][r] + bj[j];
        if (RELU) v = fmaxf(v, 0.f);
        if (OUTBF) ((ushort_t*)Cout)[(size_t)row * Ncols + colb[j]] = f2bf(v);
        else       ((float*)Cout)[(size_t)row * Ncols + colb[j]] = v;
      }
    }
  }
}

// ---------- 32x256 GEMM + residual + LayerNorm, 256 thr (4 waves), BK=64 ----------
// grid = 200 blocks (32-row tiles) for CU coverage; 2-phase pipelined K-loop.
template<bool OUTBF>
__global__ __launch_bounds__(256) void k_gemm_ln(const ushort_t* __restrict__ A,
    const ushort_t* __restrict__ W, const float* __restrict__ bias,
    const float* __restrict__ R, const float* __restrict__ gamma,
    const float* __restrict__ beta, float* __restrict__ outF,
    ushort_t* __restrict__ outB, int Kdim) {
  __shared__ __align__(16) ushort_t As[2][32 * 64];    // 8KB
  __shared__ __align__(16) ushort_t Bs[2][256 * 64];   // 64KB
  __shared__ float red_s[32 * 4];
  __shared__ float red_q[32 * 4];
  int tid = threadIdx.x;
  int wid = tid >> 6, lane = tid & 63;
  int wn = wid;
  int row0 = blockIdx.x * 32;

  const ushort_t* gA; int dofsA;
  {
    int r = tid >> 3, ck = (tid & 7) ^ (r & 7);
    gA = A + (size_t)(row0 + r) * Kdim + ck * 8;
    dofsA = (wid * 64) * 8;
  }
  const ushort_t* gB[8]; int dofsB[8];
  #pragma unroll
  for (int i = 0; i < 8; i++) {
    int s = i * 256 + tid;
    int r = s >> 3, ck = (s & 7) ^ (r & 7);
    gB[i] = W + (size_t)r * Kdim + ck * 8;
    dofsB[i] = (i * 256 + wid * 64) * 8;
  }

  f32x4 acc[2][4];
  #pragma unroll
  for (int i = 0; i < 2; i++)
    #pragma unroll
    for (int n = 0; n < 4; n++) { f32x4 z = {0.f,0.f,0.f,0.f}; acc[i][n] = z; }

  // prologue
  gll16(gA, &As[0][dofsA]);
  #pragma unroll
  for (int i = 0; i < 8; i++) gll16(gB[i], &Bs[0][dofsB[i]]);
  asm volatile("s_waitcnt vmcnt(0)" ::: "memory");
  __builtin_amdgcn_s_barrier();

  int nsteps = Kdim >> 6;
  int cur = 0;
  for (int ks = 0; ks < nsteps; ks++) {
    if (ks + 1 < nsteps) {
      int k0n = (ks + 1) << 6;
      gll16(gA + k0n, &As[cur ^ 1][dofsA]);
      #pragma unroll
      for (int i = 0; i < 8; i++) gll16(gB[i] + k0n, &Bs[cur ^ 1][dofsB[i]]);
    }
    #pragma unroll
    for (int kk = 0; kk < 2; kk++) {
      short8 af[2], bfv[4];
      #pragma unroll
      for (int i = 0; i < 2; i++) {
        int row = i * 16 + (lane & 15);
        int ck = (kk * 4 + (lane >> 4)) ^ (row & 7);
        af[i] = *(const short8*)&As[cur][row * 64 + ck * 8];
      }
      #pragma unroll
      for (int n = 0; n < 4; n++) {
        int row = wn * 64 + n * 16 + (lane & 15);
        int ck = (kk * 4 + (lane >> 4)) ^ (row & 7);
        bfv[n] = *(const short8*)&Bs[cur][row * 64 + ck * 8];
      }
      #pragma unroll
      for (int i = 0; i < 2; i++)
        #pragma unroll
        for (int n = 0; n < 4; n++)
          acc[i][n] = __builtin_amdgcn_mfma_f32_16x16x32_bf16(af[i], bfv[n], acc[i][n], 0, 0, 0);
    }
    asm volatile("s_waitcnt vmcnt(0)" ::: "memory");
    __builtin_amdgcn_s_barrier();
    cur ^= 1;
  }

  int col[4]; float bc[4], gm[4], bt[4];
  #pragma unroll
  for (int n = 0; n < 4; n++) {
    col[n] = wn * 64 + n * 16 + (lane & 15);
    bc[n] = bias[col[n]]; gm[n] = gamma[col[n]]; bt[n] = beta[col[n]];
  }
  // bias + residual; per-row partials over this wave's 64 cols
  #pragma unroll
  for (int i = 0; i < 2; i++) {
    #pragma unroll
    for (int r = 0; r < 4; r++) {
      int row_l = i * 16 + (lane >> 4) * 4 + r;
      const float* Rrow = R + (size_t)(row0 + row_l) * HD;
      float s = 0.f, q = 0.f;
      #pragma unroll
      for (int n = 0; n < 4; n++) {
        float v = acc[i][n][r] + bc[n] + Rrow[col[n]];
        acc[i][n][r] = v;
        s += v; q += v * v;
      }
      #pragma unroll
      for (int o = 1; o < 16; o <<= 1) { s += __shfl_xor(s, o, 64); q += __shfl_xor(q, o, 64); }
      if ((lane & 15) == 0) { red_s[row_l * 4 + wn] = s; red_q[row_l * 4 + wn] = q; }
    }
  }
  __syncthreads();
  #pragma unroll
  for (int i = 0; i < 2; i++) {
    #pragma unroll
    for (int r = 0; r < 4; r++) {
      int row_l = i * 16 + (lane >> 4) * 4 + r;
      float ssum = red_s[row_l * 4] + red_s[row_l * 4 + 1] + red_s[row_l * 4 + 2] + red_s[row_l * 4 + 3];
      float qsum = red_q[row_l * 4] + red_q[row_l * 4 + 1] + red_q[row_l * 4 + 2] + red_q[row_l * 4 + 3];
      float mu = ssum * (1.f / HD);
      float var = qsum * (1.f / HD) - mu * mu;
      float inv = rsqrtf(var + 1e-5f);
      size_t rb = (size_t)(row0 + row_l) * HD;
      #pragma unroll
      for (int n = 0; n < 4; n++) {
        float v = (acc[i][n][r] - mu) * inv * gm[n] + bt[n];
        outF[rb + col[n]] = v;
        if (OUTBF) outB[rb + col[n]] = f2bf(v);
      }
    }
  }
}

// ---------- fused masked attention, MFMA 32x32x16, swapped operands ----------
__global__ __launch_bounds__(256) void k_attn(const ushort_t* __restrict__ qkb,
    const u32* __restrict__ adj, const int* __restrict__ offs,
    ushort_t* __restrict__ attOb) {
  int bid = blockIdx.x;               // b(4b) | h(3b) | qtr(2b)
  int qtr = bid & 3, hh = (bid >> 2) & 7, b = bid >> 5;
  int nstart = offs[b], len = offs[b + 1] - nstart;
  int q0blk = qtr * 128;
  if (q0blk >= len) return;

  __shared__ __align__(16) ushort_t K_lds[4 * 512 * 8];    // 32KB
  __shared__ __align__(16) ushort_t Kt_lds[64 * 32 * 8];   // 32KB
  __shared__ __align__(16) ushort_t P_lds[4 * 4 * 32 * 8]; // 8KB

  int tid = threadIdx.x;
  {
    const ushort_t* kg = qkb + (size_t)(b * S_MAX) * 512 + 256 + hh * 32;
    for (int t = tid; t < 512; t += 256) {
      const uint4* src = (const uint4*)(kg + (size_t)t * 512);
      uint4 v0 = src[0], v1 = src[1], v2 = src[2], v3 = src[3];
      *(uint4*)&K_lds[0 * 4096 + t * 8] = v0;
      *(uint4*)&K_lds[1 * 4096 + t * 8] = v1;
      *(uint4*)&K_lds[2 * 4096 + t * 8] = v2;
      *(uint4*)&K_lds[3 * 4096 + t * 8] = v3;
    }
  }
  __syncthreads();
  {
    int d = tid & 31, tg = tid >> 5;
    int cc = d >> 3, e = d & 7;
    for (int i = 0; i < 8; i++) {
      int t0 = tg * 64 + i * 8;
      u32 w0 = (u32)K_lds[cc * 4096 + (t0 + 0) * 8 + e] | ((u32)K_lds[cc * 4096 + (t0 + 1) * 8 + e] << 16);
      u32 w1 = (u32)K_lds[cc * 4096 + (t0 + 2) * 8 + e] | ((u32)K_lds[cc * 4096 + (t0 + 3) * 8 + e] << 16);
      u32 w2 = (u32)K_lds[cc * 4096 + (t0 + 4) * 8 + e] | ((u32)K_lds[cc * 4096 + (t0 + 5) * 8 + e] << 16);
      u32 w3 = (u32)K_lds[cc * 4096 + (t0 + 6) * 8 + e] | ((u32)K_lds[cc * 4096 + (t0 + 7) * 8 + e] << 16);
      uint4 pk = {w0, w1, w2, w3};
      *(uint4*)&Kt_lds[(t0 >> 3) * 256 + d * 8] = pk;
    }
  }
  __syncthreads();

  int w = tid >> 6, lane = tid & 63;
  int q0w = q0blk + w * 32;
  if (q0w >= len) return;   // no barriers below

  int lq = lane & 31, hf = lane >> 5;
  int q_abs = q0w + lq;
  const float SCALE = 0.17677669529663687f;  // 1/sqrt(32)

  size_t qrow = (size_t)(b * S_MAX + q_abs) * 512 + hh * 32;
  short8 qf0 = *(const short8*)(qkb + qrow + hf * 8);
  short8 qf1 = *(const short8*)(qkb + qrow + 16 + hf * 8);

  const uint4* ap = (const uint4*)(adj + (size_t)(b * S_MAX + q_abs) * ADJW);
  uint4 a0 = ap[0], a1 = ap[1], a2 = ap[2], a3 = ap[3];
  u32 aw[16] = {a0.x, a0.y, a0.z, a0.w, a1.x, a1.y, a1.z, a1.w,
                a2.x, a2.y, a2.z, a2.w, a3.x, a3.y, a3.z, a3.w};

  f32x16 oacc = {0.f,0.f,0.f,0.f,0.f,0.f,0.f,0.f,0.f,0.f,0.f,0.f,0.f,0.f,0.f,0.f};
  float lsum = 0.f;

  #pragma unroll
  for (int tt = 0; tt < 16; tt++) {
    int t0 = tt * 32;
    short8 ka0 = *(const short8*)&K_lds[hf * 4096 + (t0 + lq) * 8];
    short8 ka1 = *(const short8*)&K_lds[(2 + hf) * 4096 + (t0 + lq) * 8];
    f32x16 sc = {0.f,0.f,0.f,0.f,0.f,0.f,0.f,0.f,0.f,0.f,0.f,0.f,0.f,0.f,0.f,0.f};
    sc = __builtin_amdgcn_mfma_f32_32x32x16_bf16(ka0, qf0, sc, 0, 0, 0);
    sc = __builtin_amdgcn_mfma_f32_32x32x16_bf16(ka1, qf1, sc, 0, 0, 0);
    u32 word = aw[tt];
    float p[16];
    #pragma unroll
    for (int r = 0; r < 16; r++) {
      int tb = (r & 3) + 8 * (r >> 2) + 4 * hf;
      float pe = __expf(sc[r] * SCALE);
      p[r] = ((word >> tb) & 1u) ? 0.f : pe;
      lsum += p[r];
    }
    #pragma unroll
    for (int g = 0; g < 4; g++) {
      u32 lo = (u32)f2bf(p[4 * g]) | ((u32)f2bf(p[4 * g + 1]) << 16);
      u32 hi = (u32)f2bf(p[4 * g + 2]) | ((u32)f2bf(p[4 * g + 3]) << 16);
      uint2 pk = {lo, hi};
      *(uint2*)&P_lds[w * 1024 + g * 256 + lq * 8 + hf * 4] = pk;
    }
    short8 va0 = *(const short8*)&Kt_lds[(t0 / 8 + hf) * 256 + lq * 8];
    short8 va1 = *(const short8*)&Kt_lds[(t0 / 8 + 2 + hf) * 256 + lq * 8];
    short8 pb0 = *(const short8*)&P_lds[w * 1024 + hf * 256 + lq * 8];
    short8 pb1 = *(const short8*)&P_lds[w * 1024 + (2 + hf) * 256 + lq * 8];
    oacc = __builtin_amdgcn_mfma_f32_32x32x16_bf16(va0, pb0, oacc, 0, 0, 0);
    oacc = __builtin_amdgcn_mfma_f32_32x32x16_bf16(va1, pb1, oacc, 0, 0, 0);
  }

  float ltot = lsum + __shfl_xor(lsum, 32, 64);
  float inv = 1.f / ltot;
  if (q_abs < len) {
    int node = nstart + q_abs;
    ushort_t* op = attOb + (size_t)node * HD + hh * DH;
    #pragma unroll
    for (int g = 0; g < 4; g++) {
      float v0 = oacc[4 * g] * inv, v1 = oacc[4 * g + 1] * inv;
      float v2 = oacc[4 * g + 2] * inv, v3 = oacc[4 * g + 3] * inv;
      u32 lo = (u32)f2bf(v0) | ((u32)f2bf(v1) << 16);
      u32 hi = (u32)f2bf(v2) | ((u32)f2bf(v3) << 16);
      uint2 pk = {lo, hi};
      *(uint2*)(op + g * 8 + hf * 4) = pk;
    }
  }
}

extern "C" void kernel_launch(void* const* d_in, const int* in_sizes, int n_in,
                              void* d_out, int out_size, void* d_ws, size_t ws_size,
                              hipStream_t stream) {
  const float* h   = (const float*)d_in[0];
  const float* Wq  = (const float*)d_in[1];
  const float* bq  = (const float*)d_in[2];
  const float* Wk  = (const float*)d_in[3];
  const float* bk  = (const float*)d_in[4];
  // d_in[5], d_in[6] (Wv, bv) unused: reference V uses the K projection
  const float* Wo  = (const float*)d_in[7];
  const float* bo  = (const float*)d_in[8];
  const float* W1  = (const float*)d_in[9];
  const float* b1  = (const float*)d_in[10];
  const float* W2  = (const float*)d_in[11];
  const float* b2  = (const float*)d_in[12];
  const float* g1  = (const float*)d_in[13];
  const float* be1 = (const float*)d_in[14];
  const float* g2  = (const float*)d_in[15];
  const float* be2 = (const float*)d_in[16];
  const int* batch = (const int*)d_in[17];
  const int* ei    = (const int*)d_in[18];
  int N = in_sizes[0] / HD;       // 6400
  int E = in_sizes[18] / 2;       // 102400

  // workspace layout (~38 MB)
  char* ws = (char*)d_ws;
  ushort_t* xb    = (ushort_t*)(ws);                        // 4MB [8192,256] bf16 (later attO)
  ushort_t* attOb = xb;
  ushort_t* qkb   = (ushort_t*)(ws + ((size_t)4 << 20));    // 8MB [8192,512] bf16
  float*    h1    = (float*)(ws + ((size_t)12 << 20));      // 6.4MB fp32
  ushort_t* h1b   = (ushort_t*)(ws + ((size_t)19 << 20));   // 3.2MB
  ushort_t* ff1b  = (ushort_t*)(ws + ((size_t)23 << 20));   // 12.8MB
  char* wbase = ws + ((size_t)36 << 20);
  ushort_t* Wqkb = (ushort_t*)(wbase);                      // 256KB [512,256]
  ushort_t* Wob  = (ushort_t*)(wbase + (256 << 10));        // 128KB
  ushort_t* W1b  = (ushort_t*)(wbase + (384 << 10));        // 512KB [1024,256]
  ushort_t* W2b  = (ushort_t*)(wbase + (896 << 10));        // 512KB [256,1024]
  float*    bqk  = (float*)(wbase + (1408 << 10));          // 2KB  [512]
  u32*      adj  = (u32*)(wbase + (1536 << 10));            // 512KB
  int*      offs = (int*)(ws + ((size_t)38 << 20));         // 128B

  k_prep<<<128, 256, 0, stream>>>(adj, batch, N, offs, bq, bk, bqk);
  k_mega<<<2800, 256, 0, stream>>>(h, offs, xb, ei, E, batch, adj,
                                   Wq, Wk, Wo, W1, W2,
                                   Wqkb, Wqkb + 65536, Wob, W1b, W2b);
  // fused Q|K projection: [8192,256] x [512,256]^T -> [8192,512] bf16
  k_mgemm<false, true><<<dim3(64, 4), 512, 0, stream>>>(xb, Wqkb, bqk, qkb, 512, HD);
  // attention -> compact [6400,256] bf16
  k_attn<<<B_G * NH * 4, 256, 0, stream>>>(qkb, adj, offs, attOb);
  // out-proj + residual(h) + LN1 -> h1 (fp32) + h1b (bf16)
  k_gemm_ln<true><<<200, 256, 0, stream>>>(attOb, Wob, bo, h, g1, be1, h1, h1b, HD);
  // FFN up + relu
  k_mgemm<true, true><<<dim3(50, 8), 512, 0, stream>>>(h1b, W1b, b1, ff1b, FFD, HD);
  // FFN down + residual(h1) + LN2 -> d_out (fp32)
  k_gemm_ln<false><<<200, 256, 0, stream>>>(ff1b, W2b, b2, h1, g2, be2, (float*)d_out, nullptr, FFD);
}

// Round 8
// 88.069 us; speedup vs baseline: 3.0602x; 1.0293x over previous
//
#include <hip/hip_runtime.h>
#include <math.h>

typedef unsigned int u32;
typedef unsigned short ushort_t;
typedef __attribute__((ext_vector_type(8))) short short8;
typedef __attribute__((ext_vector_type(4))) float f32x4;
typedef __attribute__((ext_vector_type(16))) float f32x16;

#define B_G 16
#define S_MAX 512
#define NH 8
#define DH 32
#define HD 256
#define FFD 1024
#define ADJW 16            // u32 words per adjacency row (512 bits)

__device__ __forceinline__ ushort_t f2bf(float f) {
  u32 u = __float_as_uint(f);
  u += 0x7fffu + ((u >> 16) & 1u);
  return (ushort_t)(u >> 16);
}
__device__ __forceinline__ float bf2f(ushort_t s) {
  return __uint_as_float(((u32)s) << 16);
}

__device__ __forceinline__ void gll16(const void* g, void* l) {
  __builtin_amdgcn_global_load_lds(
      (const __attribute__((address_space(1))) unsigned int*)g,
      (__attribute__((address_space(3))) unsigned int*)l, 16, 0, 0);
}

// ---------- prep: zero adj | offsets+bias | weight cvt | h cvt (compact) ----------
// blocks [0,128): adj zero (512KB); 128: offsets+bqk; [129,481): weight cvt;
// [481,1281): h fp32->bf16 compact (6400x256).
__global__ __launch_bounds__(256) void k_prep2(u32* __restrict__ adj,
    const int* __restrict__ batch, int N, int* __restrict__ offs,
    const float* __restrict__ bq, const float* __restrict__ bk, float* __restrict__ bqk,
    const float* __restrict__ wa, const float* __restrict__ wb, const float* __restrict__ wc,
    const float* __restrict__ wd, const float* __restrict__ we,
    ushort_t* __restrict__ oa, ushort_t* __restrict__ ob, ushort_t* __restrict__ oc,
    ushort_t* __restrict__ od, ushort_t* __restrict__ oe,
    const float* __restrict__ h, ushort_t* __restrict__ hb) {
  int blk = blockIdx.x, tid = threadIdx.x;
  if (blk < 128) {
    uint4 z = {0u, 0u, 0u, 0u};
    ((uint4*)adj)[blk * 256 + tid] = z;
  } else if (blk == 128) {
    bqk[tid] = bq[tid];
    bqk[HD + tid] = bk[tid];
    if (tid <= B_G) {
      if (tid == B_G) { offs[B_G] = N; }
      else {
        int lo = 0, hi = N;
        while (lo < hi) { int mid = (lo + hi) >> 1; if (batch[mid] < tid) lo = mid + 1; else hi = mid; }
        offs[tid] = lo;
      }
    }
  } else if (blk < 481) {
    int bb = blk - 129;
    const float* src; ushort_t* dst; int off;
    if (bb < 32)       { src = wa; dst = oa; off = bb; }
    else if (bb < 64)  { src = wb; dst = ob; off = bb - 32; }
    else if (bb < 96)  { src = wc; dst = oc; off = bb - 64; }
    else if (bb < 224) { src = wd; dst = od; off = bb - 96; }
    else               { src = we; dst = oe; off = bb - 224; }
    size_t i = (size_t)off * 2048 + tid * 8;
    float4 v0 = *(const float4*)&src[i];
    float4 v1 = *(const float4*)&src[i + 4];
    uint4 pk;
    pk.x = (u32)f2bf(v0.x) | ((u32)f2bf(v0.y) << 16);
    pk.y = (u32)f2bf(v0.z) | ((u32)f2bf(v0.w) << 16);
    pk.z = (u32)f2bf(v1.x) | ((u32)f2bf(v1.y) << 16);
    pk.w = (u32)f2bf(v1.z) | ((u32)f2bf(v1.w) << 16);
    *(uint4*)&dst[i] = pk;
  } else {
    size_t i = ((size_t)(blk - 481) * 256 + tid) * 8;
    float4 v0 = *(const float4*)&h[i];
    float4 v1 = *(const float4*)&h[i + 4];
    uint4 pk;
    pk.x = (u32)f2bf(v0.x) | ((u32)f2bf(v0.y) << 16);
    pk.y = (u32)f2bf(v0.z) | ((u32)f2bf(v0.w) << 16);
    pk.z = (u32)f2bf(v1.x) | ((u32)f2bf(v1.y) << 16);
    pk.w = (u32)f2bf(v1.z) | ((u32)f2bf(v1.w) << 16);
    *(uint4*)&hb[i] = pk;
  }
}

// ---------- MFMA bf16 GEMM, 64x128 tile, BK=64, 256 thr (4 waves 2x2) ----------
// 2-phase pipelined (issue next K-tile DMA before compute, one vmcnt(0)/step).
// DOEDGE: fold edge->adj atomicOr into this kernel (1 edge/thread).
template<bool RELU, bool DOEDGE>
__global__ __launch_bounds__(256) void k_mgemm(const ushort_t* __restrict__ A,
    const ushort_t* __restrict__ W, const float* __restrict__ bias,
    ushort_t* __restrict__ Cout, int Ncols, int Kdim, int gridx,
    const int* __restrict__ ei, int E, const int* __restrict__ batch,
    const int* __restrict__ offs, u32* __restrict__ adj) {
  __shared__ __align__(16) ushort_t As[2][64 * 64];    // 16KB
  __shared__ __align__(16) ushort_t Bs[2][128 * 64];   // 32KB
  int tid = threadIdx.x;
  int wid = tid >> 6, lane = tid & 63;
  int wm = wid & 1, wn = wid >> 1;
  int arow0 = blockIdx.x * 64, bcol0 = blockIdx.y * 128;

  if (DOEDGE) {
    int e = (blockIdx.y * gridx + blockIdx.x) * 256 + tid;
    if (e < E) {
      int s = ei[e], d = ei[E + e];
      int b = batch[s];
      int o = offs[b];
      atomicOr(&adj[(b * S_MAX + (s - o)) * ADJW + ((d - o) >> 5)], 1u << ((d - o) & 31));
    }
  }

  const ushort_t* gA[2]; const ushort_t* gB[4];
  int dofsA[2], dofsB[4];
  #pragma unroll
  for (int i = 0; i < 2; i++) {
    int s = i * 256 + wid * 64 + lane;
    int r = s >> 3, ck = (s & 7) ^ (r & 7);
    gA[i] = A + (size_t)(arow0 + r) * Kdim + ck * 8;
    dofsA[i] = (i * 256 + wid * 64) * 8;
  }
  #pragma unroll
  for (int i = 0; i < 4; i++) {
    int s = i * 256 + wid * 64 + lane;
    int r = s >> 3, ck = (s & 7) ^ (r & 7);
    gB[i] = W + (size_t)(bcol0 + r) * Kdim + ck * 8;
    dofsB[i] = (i * 256 + wid * 64) * 8;
  }

  f32x4 acc[2][4];
  #pragma unroll
  for (int i = 0; i < 2; i++)
    #pragma unroll
    for (int j = 0; j < 4; j++) { f32x4 z = {0.f,0.f,0.f,0.f}; acc[i][j] = z; }

  #pragma unroll
  for (int i = 0; i < 2; i++) gll16(gA[i], &As[0][dofsA[i]]);
  #pragma unroll
  for (int i = 0; i < 4; i++) gll16(gB[i], &Bs[0][dofsB[i]]);
  asm volatile("s_waitcnt vmcnt(0)" ::: "memory");
  __builtin_amdgcn_s_barrier();

  int nsteps = Kdim >> 6;
  int cur = 0;
  for (int ks = 0; ks < nsteps; ks++) {
    if (ks + 1 < nsteps) {
      int k0n = (ks + 1) << 6;
      #pragma unroll
      for (int i = 0; i < 2; i++) gll16(gA[i] + k0n, &As[cur ^ 1][dofsA[i]]);
      #pragma unroll
      for (int i = 0; i < 4; i++) gll16(gB[i] + k0n, &Bs[cur ^ 1][dofsB[i]]);
    }
    #pragma unroll
    for (int kk = 0; kk < 2; kk++) {
      short8 af[2], bfv[4];
      #pragma unroll
      for (int i = 0; i < 2; i++) {
        int row = wm * 32 + i * 16 + (lane & 15);
        int ck = (kk * 4 + (lane >> 4)) ^ (row & 7);
        af[i] = *(const short8*)&As[cur][row * 64 + ck * 8];
      }
      #pragma unroll
      for (int j = 0; j < 4; j++) {
        int row = wn * 64 + j * 16 + (lane & 15);
        int ck = (kk * 4 + (lane >> 4)) ^ (row & 7);
        bfv[j] = *(const short8*)&Bs[cur][row * 64 + ck * 8];
      }
      #pragma unroll
      for (int i = 0; i < 2; i++)
        #pragma unroll
        for (int j = 0; j < 4; j++)
          acc[i][j] = __builtin_amdgcn_mfma_f32_16x16x32_bf16(af[i], bfv[j], acc[i][j], 0, 0, 0);
    }
    asm volatile("s_waitcnt vmcnt(0)" ::: "memory");
    __builtin_amdgcn_s_barrier();
    cur ^= 1;
  }

  float bj[4]; int colb[4];
  #pragma unroll
  for (int j = 0; j < 4; j++) {
    colb[j] = bcol0 + wn * 64 + j * 16 + (lane & 15);
    bj[j] = bias[colb[j]];
  }
  #pragma unroll
  for (int i = 0; i < 2; i++) {
    #pragma unroll
    for (int r = 0; r < 4; r++) {
      int row = arow0 + wm * 32 + i * 16 + (lane >> 4) * 4 + r;
      #pragma unroll
      for (int j = 0; j < 4; j++) {
        float v = acc[i][j][r] + bj[j];
        if (RELU) v = fmaxf(v, 0.f);
        Cout[(size_t)row * Ncols + colb[j]] = f2bf(v);
      }
    }
  }
}

// ---------- 32x256 GEMM + residual + LayerNorm, 256 thr (4 waves), BK=64 ----------
template<bool OUTBF>
__global__ __launch_bounds__(256) void k_gemm_ln(const ushort_t* __restrict__ A,
    const ushort_t* __restrict__ W, const float* __restrict__ bias,
    const float* __restrict__ R, const float* __restrict__ gamma,
    const float* __restrict__ beta, float* __restrict__ outF,
    ushort_t* __restrict__ outB, int Kdim) {
  __shared__ __align__(16) ushort_t As[2][32 * 64];    // 8KB
  __shared__ __align__(16) ushort_t Bs[2][256 * 64];   // 64KB
  __shared__ float red_s[32 * 4];
  __shared__ float red_q[32 * 4];
  int tid = threadIdx.x;
  int wid = tid >> 6, lane = tid & 63;
  int wn = wid;
  int row0 = blockIdx.x * 32;

  const ushort_t* gA; int dofsA;
  {
    int r = tid >> 3, ck = (tid & 7) ^ (r & 7);
    gA = A + (size_t)(row0 + r) * Kdim + ck * 8;
    dofsA = (wid * 64) * 8;
  }
  const ushort_t* gB[8]; int dofsB[8];
  #pragma unroll
  for (int i = 0; i < 8; i++) {
    int s = i * 256 + tid;
    int r = s >> 3, ck = (s & 7) ^ (r & 7);
    gB[i] = W + (size_t)r * Kdim + ck * 8;
    dofsB[i] = (i * 256 + wid * 64) * 8;
  }

  f32x4 acc[2][4];
  #pragma unroll
  for (int i = 0; i < 2; i++)
    #pragma unroll
    for (int n = 0; n < 4; n++) { f32x4 z = {0.f,0.f,0.f,0.f}; acc[i][n] = z; }

  gll16(gA, &As[0][dofsA]);
  #pragma unroll
  for (int i = 0; i < 8; i++) gll16(gB[i], &Bs[0][dofsB[i]]);
  asm volatile("s_waitcnt vmcnt(0)" ::: "memory");
  __builtin_amdgcn_s_barrier();

  int nsteps = Kdim >> 6;
  int cur = 0;
  for (int ks = 0; ks < nsteps; ks++) {
    if (ks + 1 < nsteps) {
      int k0n = (ks + 1) << 6;
      gll16(gA + k0n, &As[cur ^ 1][dofsA]);
      #pragma unroll
      for (int i = 0; i < 8; i++) gll16(gB[i] + k0n, &Bs[cur ^ 1][dofsB[i]]);
    }
    #pragma unroll
    for (int kk = 0; kk < 2; kk++) {
      short8 af[2], bfv[4];
      #pragma unroll
      for (int i = 0; i < 2; i++) {
        int row = i * 16 + (lane & 15);
        int ck = (kk * 4 + (lane >> 4)) ^ (row & 7);
        af[i] = *(const short8*)&As[cur][row * 64 + ck * 8];
      }
      #pragma unroll
      for (int n = 0; n < 4; n++) {
        int row = wn * 64 + n * 16 + (lane & 15);
        int ck = (kk * 4 + (lane >> 4)) ^ (row & 7);
        bfv[n] = *(const short8*)&Bs[cur][row * 64 + ck * 8];
      }
      #pragma unroll
      for (int i = 0; i < 2; i++)
        #pragma unroll
        for (int n = 0; n < 4; n++)
          acc[i][n] = __builtin_amdgcn_mfma_f32_16x16x32_bf16(af[i], bfv[n], acc[i][n], 0, 0, 0);
    }
    asm volatile("s_waitcnt vmcnt(0)" ::: "memory");
    __builtin_amdgcn_s_barrier();
    cur ^= 1;
  }

  int col[4]; float bc[4], gm[4], bt[4];
  #pragma unroll
  for (int n = 0; n < 4; n++) {
    col[n] = wn * 64 + n * 16 + (lane & 15);
    bc[n] = bias[col[n]]; gm[n] = gamma[col[n]]; bt[n] = beta[col[n]];
  }
  #pragma unroll
  for (int i = 0; i < 2; i++) {
    #pragma unroll
    for (int r = 0; r < 4; r++) {
      int row_l = i * 16 + (lane >> 4) * 4 + r;
      const float* Rrow = R + (size_t)(row0 + row_l) * HD;
      float s = 0.f, q = 0.f;
      #pragma unroll
      for (int n = 0; n < 4; n++) {
        float v = acc[i][n][r] + bc[n] + Rrow[col[n]];
        acc[i][n][r] = v;
        s += v; q += v * v;
      }
      #pragma unroll
      for (int o = 1; o < 16; o <<= 1) { s += __shfl_xor(s, o, 64); q += __shfl_xor(q, o, 64); }
      if ((lane & 15) == 0) { red_s[row_l * 4 + wn] = s; red_q[row_l * 4 + wn] = q; }
    }
  }
  __syncthreads();
  #pragma unroll
  for (int i = 0; i < 2; i++) {
    #pragma unroll
    for (int r = 0; r < 4; r++) {
      int row_l = i * 16 + (lane >> 4) * 4 + r;
      float ssum = red_s[row_l * 4] + red_s[row_l * 4 + 1] + red_s[row_l * 4 + 2] + red_s[row_l * 4 + 3];
      float qsum = red_q[row_l * 4] + red_q[row_l * 4 + 1] + red_q[row_l * 4 + 2] + red_q[row_l * 4 + 3];
      float mu = ssum * (1.f / HD);
      float var = qsum * (1.f / HD) - mu * mu;
      float inv = rsqrtf(var + 1e-5f);
      size_t rb = (size_t)(row0 + row_l) * HD;
      #pragma unroll
      for (int n = 0; n < 4; n++) {
        float v = (acc[i][n][r] - mu) * inv * gm[n] + bt[n];
        outF[rb + col[n]] = v;
        if (OUTBF) outB[rb + col[n]] = f2bf(v);
      }
    }
  }
}

// ---------- fused masked attention, compact rows, analytic padding term ----------
// K/V iterated only over real columns [0,len); the (512-len) padding columns all
// have k=v=bk (K-proj of zero row), contributing pad*exp(q.bk*s) to the denom and
// pad*exp(q.bk*s)*bk[d] to the numerator -- added in closed form per q-row.
__global__ __launch_bounds__(256) void k_attn(const ushort_t* __restrict__ qkb,
    const u32* __restrict__ adj, const int* __restrict__ offs,
    const float* __restrict__ bqk, ushort_t* __restrict__ attOb) {
  int bid = blockIdx.x;               // b(4b) | h(3b) | qtr(2b)
  int qtr = bid & 3, hh = (bid >> 2) & 7, b = bid >> 5;
  int nstart = offs[b], len = offs[b + 1] - nstart;
  int q0blk = qtr * 128;
  if (q0blk >= len) return;
  int lenT = len >> 5;                // len % 32 == 0 for all graphs

  __shared__ __align__(16) ushort_t K_lds[4 * 512 * 8];    // 32KB
  __shared__ __align__(16) ushort_t Kt_lds[64 * 32 * 8];   // 32KB
  __shared__ __align__(16) ushort_t P_lds[4 * 4 * 32 * 8]; // 8KB

  int tid = threadIdx.x;
  {
    const ushort_t* kg = qkb + (size_t)nstart * 512 + 256 + hh * 32;
    for (int t = tid; t < len; t += 256) {
      const uint4* src = (const uint4*)(kg + (size_t)t * 512);
      uint4 v0 = src[0], v1 = src[1], v2 = src[2], v3 = src[3];
      *(uint4*)&K_lds[0 * 4096 + t * 8] = v0;
      *(uint4*)&K_lds[1 * 4096 + t * 8] = v1;
      *(uint4*)&K_lds[2 * 4096 + t * 8] = v2;
      *(uint4*)&K_lds[3 * 4096 + t * 8] = v3;
    }
  }
  __syncthreads();
  {
    int d = tid & 31, tg = tid >> 5;
    int cc = d >> 3, e = d & 7;
    for (int i = 0; i < 8; i++) {
      int t0 = tg * 64 + i * 8;
      if (t0 < len) {
        u32 w0 = (u32)K_lds[cc * 4096 + (t0 + 0) * 8 + e] | ((u32)K_lds[cc * 4096 + (t0 + 1) * 8 + e] << 16);
        u32 w1 = (u32)K_lds[cc * 4096 + (t0 + 2) * 8 + e] | ((u32)K_lds[cc * 4096 + (t0 + 3) * 8 + e] << 16);
        u32 w2 = (u32)K_lds[cc * 4096 + (t0 + 4) * 8 + e] | ((u32)K_lds[cc * 4096 + (t0 + 5) * 8 + e] << 16);
        u32 w3 = (u32)K_lds[cc * 4096 + (t0 + 6) * 8 + e] | ((u32)K_lds[cc * 4096 + (t0 + 7) * 8 + e] << 16);
        uint4 pk = {w0, w1, w2, w3};
        *(uint4*)&Kt_lds[(t0 >> 3) * 256 + d * 8] = pk;
      }
    }
  }
  __syncthreads();

  int w = tid >> 6, lane = tid & 63;
  int q0w = q0blk + w * 32;
  if (q0w >= len) return;   // no barriers below

  int lq = lane & 31, hf = lane >> 5;
  const float SCALE = 0.17677669529663687f;  // 1/sqrt(32)

  size_t qrow = (size_t)(nstart + q0w + lq) * 512 + hh * 32;
  short8 qf0 = *(const short8*)(qkb + qrow + hf * 8);
  short8 qf1 = *(const short8*)(qkb + qrow + 16 + hf * 8);

  const uint4* ap = (const uint4*)(adj + (size_t)(b * S_MAX + q0w + lq) * ADJW);
  uint4 a0 = ap[0], a1 = ap[1], a2 = ap[2], a3 = ap[3];
  u32 aw[16] = {a0.x, a0.y, a0.z, a0.w, a1.x, a1.y, a1.z, a1.w,
                a2.x, a2.y, a2.z, a2.w, a3.x, a3.y, a3.z, a3.w};

  f32x16 oacc = {0.f,0.f,0.f,0.f,0.f,0.f,0.f,0.f,0.f,0.f,0.f,0.f,0.f,0.f,0.f,0.f};
  float lsum = 0.f;

  for (int tt = 0; tt < lenT; tt++) {
    int t0 = tt * 32;
    short8 ka0 = *(const short8*)&K_lds[hf * 4096 + (t0 + lq) * 8];
    short8 ka1 = *(const short8*)&K_lds[(2 + hf) * 4096 + (t0 + lq) * 8];
    f32x16 sc = {0.f,0.f,0.f,0.f,0.f,0.f,0.f,0.f,0.f,0.f,0.f,0.f,0.f,0.f,0.f,0.f};
    sc = __builtin_amdgcn_mfma_f32_32x32x16_bf16(ka0, qf0, sc, 0, 0, 0);
    sc = __builtin_amdgcn_mfma_f32_32x32x16_bf16(ka1, qf1, sc, 0, 0, 0);
    u32 word = aw[tt];
    float p[16];
    #pragma unroll
    for (int r = 0; r < 16; r++) {
      int tb = (r & 3) + 8 * (r >> 2) + 4 * hf;
      float pe = __expf(sc[r] * SCALE);
      p[r] = ((word >> tb) & 1u) ? 0.f : pe;
      lsum += p[r];
    }
    #pragma unroll
    for (int g = 0; g < 4; g++) {
      u32 lo = (u32)f2bf(p[4 * g]) | ((u32)f2bf(p[4 * g + 1]) << 16);
      u32 hi = (u32)f2bf(p[4 * g + 2]) | ((u32)f2bf(p[4 * g + 3]) << 16);
      uint2 pk = {lo, hi};
      *(uint2*)&P_lds[w * 1024 + g * 256 + lq * 8 + hf * 4] = pk;
    }
    short8 va0 = *(const short8*)&Kt_lds[(t0 / 8 + hf) * 256 + lq * 8];
    short8 va1 = *(const short8*)&Kt_lds[(t0 / 8 + 2 + hf) * 256 + lq * 8];
    short8 pb0 = *(const short8*)&P_lds[w * 1024 + hf * 256 + lq * 8];
    short8 pb1 = *(const short8*)&P_lds[w * 1024 + (2 + hf) * 256 + lq * 8];
    oacc = __builtin_amdgcn_mfma_f32_32x32x16_bf16(va0, pb0, oacc, 0, 0, 0);
    oacc = __builtin_amdgcn_mfma_f32_32x32x16_bf16(va1, pb1, oacc, 0, 0, 0);
  }

  // analytic padding: pad columns have k = v = bk_head (zero row + bias)
  const float* bkh = bqk + 256 + hh * 32;
  float pq = 0.f;
  #pragma unroll
  for (int j = 0; j < 8; j++) pq += bf2f((ushort_t)qf0[j]) * bkh[hf * 8 + j];
  #pragma unroll
  for (int j = 0; j < 8; j++) pq += bf2f((ushort_t)qf1[j]) * bkh[16 + hf * 8 + j];
  pq += __shfl_xor(pq, 32, 64);
  float pe_pad = __expf(pq * SCALE) * (float)(S_MAX - len);

  float ltot = lsum + __shfl_xor(lsum, 32, 64) + pe_pad;
  float inv = 1.f / ltot;
  {
    int node = nstart + q0w + lq;
    ushort_t* op = attOb + (size_t)node * HD + hh * DH;
    #pragma unroll
    for (int g = 0; g < 4; g++) {
      float v0 = (oacc[4 * g]     + pe_pad * bkh[g * 8 + hf * 4 + 0]) * inv;
      float v1 = (oacc[4 * g + 1] + pe_pad * bkh[g * 8 + hf * 4 + 1]) * inv;
      float v2 = (oacc[4 * g + 2] + pe_pad * bkh[g * 8 + hf * 4 + 2]) * inv;
      float v3 = (oacc[4 * g + 3] + pe_pad * bkh[g * 8 + hf * 4 + 3]) * inv;
      u32 lo = (u32)f2bf(v0) | ((u32)f2bf(v1) << 16);
      u32 hi = (u32)f2bf(v2) | ((u32)f2bf(v3) << 16);
      uint2 pk = {lo, hi};
      *(uint2*)(op + g * 8 + hf * 4) = pk;
    }
  }
}

extern "C" void kernel_launch(void* const* d_in, const int* in_sizes, int n_in,
                              void* d_out, int out_size, void* d_ws, size_t ws_size,
                              hipStream_t stream) {
  const float* h   = (const float*)d_in[0];
  const float* Wq  = (const float*)d_in[1];
  const float* bq  = (const float*)d_in[2];
  const float* Wk  = (const float*)d_in[3];
  const float* bk  = (const float*)d_in[4];
  // d_in[5], d_in[6] (Wv, bv) unused: reference V uses the K projection
  const float* Wo  = (const float*)d_in[7];
  const float* bo  = (const float*)d_in[8];
  const float* W1  = (const float*)d_in[9];
  const float* b1  = (const float*)d_in[10];
  const float* W2  = (const float*)d_in[11];
  const float* b2  = (const float*)d_in[12];
  const float* g1  = (const float*)d_in[13];
  const float* be1 = (const float*)d_in[14];
  const float* g2  = (const float*)d_in[15];
  const float* be2 = (const float*)d_in[16];
  const int* batch = (const int*)d_in[17];
  const int* ei    = (const int*)d_in[18];
  int N = in_sizes[0] / HD;       // 6400
  int E = in_sizes[18] / 2;       // 102400

  // workspace layout (~32 MB), all compact [6400,*]
  char* ws = (char*)d_ws;
  ushort_t* hb    = (ushort_t*)(ws);                        // 3.2MB [6400,256] bf16 (later attO)
  ushort_t* attOb = hb;
  ushort_t* qkb   = (ushort_t*)(ws + ((size_t)4 << 20));    // 6.4MB [6400,512] bf16
  float*    h1    = (float*)(ws + ((size_t)12 << 20));      // 6.4MB fp32
  ushort_t* h1b   = (ushort_t*)(ws + ((size_t)19 << 20));   // 3.2MB
  ushort_t* ff1b  = (ushort_t*)(ws + ((size_t)23 << 20));   // 12.8MB
  char* wbase = ws + ((size_t)36 << 20);
  ushort_t* Wqkb = (ushort_t*)(wbase);                      // 256KB [512,256]
  ushort_t* Wob  = (ushort_t*)(wbase + (256 << 10));        // 128KB
  ushort_t* W1b  = (ushort_t*)(wbase + (384 << 10));        // 512KB [1024,256]
  ushort_t* W2b  = (ushort_t*)(wbase + (896 << 10));        // 512KB [256,1024]
  float*    bqk  = (float*)(wbase + (1408 << 10));          // 2KB  [512]
  u32*      adj  = (u32*)(wbase + (1536 << 10));            // 512KB
  int*      offs = (int*)(ws + ((size_t)38 << 20));         // 128B

  // P1: adj zero | offsets+bias | weight cvt | compact h cvt
  k_prep2<<<1281, 256, 0, stream>>>(adj, batch, N, offs, bq, bk, bqk,
                                    Wq, Wk, Wo, W1, W2,
                                    Wqkb, Wqkb + 65536, Wob, W1b, W2b, h, hb);
  // P2: fused Q|K projection on compact rows + edge atomics (1 edge/thread)
  k_mgemm<false, true><<<dim3(100, 4), 256, 0, stream>>>(hb, Wqkb, bqk, qkb, 512, HD, 100,
                                                         ei, E, batch, offs, adj);
  // P3: attention (compact, analytic padding) -> attOb
  k_attn<<<B_G * NH * 4, 256, 0, stream>>>(qkb, adj, offs, bqk, attOb);
  // P4: out-proj + residual(h) + LN1 -> h1 (fp32) + h1b (bf16)
  k_gemm_ln<true><<<200, 256, 0, stream>>>(attOb, Wob, bo, h, g1, be1, h1, h1b, HD);
  // P5: FFN up + relu
  k_mgemm<true, false><<<dim3(100, 8), 256, 0, stream>>>(h1b, W1b, b1, ff1b, FFD, HD, 100,
                                                         nullptr, 0, nullptr, nullptr, nullptr);
  // P6: FFN down + residual(h1) + LN2 -> d_out (fp32)
  k_gemm_ln<false><<<200, 256, 0, stream>>>(ff1b, W2b, b2, h1, g2, be2, (float*)d_out, nullptr, FFD);
}